// Round 7
// baseline (168.823 us; speedup 1.0000x reference)
//
#include <hip/hip_runtime.h>
#include <math.h>

namespace {
constexpr int kUnits = 128;
constexpr int kSteps = 2048;
constexpr int kBatch = 32;
constexpr int kSeg = 16;                       // linearization window (r0-proven)
constexpr int kNSeg = kSteps / kSeg;           // 128 segments per chain
constexpr int kSegB = kNSeg / 2;               // 64 own segments per block
constexpr int kUBlk = 16;                      // units per block: full 64B lines
constexpr int kUPT = 2;                        // units per thread (float2)
constexpr int kUG = kUBlk / kUPT;              // 8 u-groups
constexpr int kThreads = kUG * kSegB;          // 512 threads/block
constexpr int kBlocks = kBatch * (kUnits / kUBlk) * 2;  // 512 -> 2 blocks/CU
constexpr int kGrp = 16;                       // global scan groups (8 used by half0)
constexpr int kGrpSeg = kNSeg / kGrp;          // 8 segments per group
constexpr int kPad = kUBlk + 1;                // LDS pad
constexpr double kDT = 1.0 / 173.61;
constexpr double kTwoPi = 6.283185307179586;
constexpr double kInv2Pi = 1.0 / kTwoPi;
constexpr size_t kChainElems = (size_t)kSteps * kUnits;

typedef float v2f __attribute__((ext_vector_type(2)));

// Zero-input deterministic r trajectory (identical for every chain) and the
// linear growth factors G_t = 1 + (1 - 3*beta*rbar^2)*dt, at compile time.
struct Tables {
  float G[kSteps];
  float Gseg[kNSeg];   // product of G over each segment
  float Gg[kGrp];      // product of Gseg over each scan group
  float rbar0[kNSeg];  // rbar at segment starts
};
constexpr Tables make_tables() {
  Tables tb{};
  double r = 1.0;
  for (int t = 0; t < kSteps; ++t) {
    if (t % kSeg == 0) tb.rbar0[t / kSeg] = (float)r;
    tb.G[t] = (float)(1.0 + (1.0 - 0.03 * r * r) * kDT);
    r = r + (1.0 - 0.01 * r * r) * r * kDT;
  }
  for (int s = 0; s < kNSeg; ++s) {
    double p = 1.0;
    for (int j = 0; j < kSeg; ++j) p *= (double)tb.G[s * kSeg + j];
    tb.Gseg[s] = (float)p;
  }
  for (int g = 0; g < kGrp; ++g) {
    double p = 1.0;
    for (int s = 0; s < kGrpSeg; ++s) p *= (double)tb.Gseg[g * kGrpSeg + s];
    tb.Gg[g] = (float)p;
  }
  return tb;
}
}  // namespace

__constant__ Tables kTab = make_tables();

// Time-split-by-recompute: block = (b, uq, half), 512 blocks -> 2 blocks/CU.
// Half-1 blocks RECOMPUTE the first half's 64 segment maps (streaming X,
// same fp composition order as the r0 scan -> exact seam, NO cross-block
// communication, plain launch). Redundant X re-read is paired on the same
// XCD (bid and bid+256, 256%8==0) so L2/L3 absorbs most of it. Two blocks
// per CU overlap each other's load/scan/store phases.
// Keeps the r6-validated pieces: X reg-cache + sched_barrier MLP hoist,
// f32 delta-rotation phase-3 seed (no f64 on the post-barrier path).
__global__ __launch_bounds__(kThreads, 4)
void hopf_fused(const float* __restrict__ Xr, const float* __restrict__ Xi,
                const float* __restrict__ Om,
                float* __restrict__ Zr, float* __restrict__ Zi) {
  __shared__ float sG[kNSeg][kPad];   // maps, then delta0 after phase2
  __shared__ float sH[kNSeg][kPad];   // maps, then rho0 after phase2
  __shared__ float sP[kNSeg][kPad];
  __shared__ float sQ[kNSeg][kPad];
  __shared__ float cG[kGrp][kPad], cH[kGrp][kPad], cP[kGrp][kPad], cQ[kGrp][kPad];
  __shared__ float pD[kGrp][kPad], pR[kGrp][kPad];

  const int tid = threadIdx.x;
  const int ug = tid & (kUG - 1);     // 0..7
  const int segL = tid >> 3;          // 0..63 (own local segment)
  const int bid = blockIdx.x;
  const int half = bid >> 8;          // pair (rest, rest+256): same XCD
  const int rest = bid & 255;
  const int b = rest >> 3;            // 0..31
  const int uq = rest & 7;            // 0..7
  const int u0 = uq * kUBlk + ug * kUPT;
  const int sOwn = (half << 6) + segL;   // global segment this thread replays
  const int t0 = sOwn * kSeg;

  // ---- own-segment X cache, loads pinned above compute for MLP (r6) ----
  const size_t base = ((size_t)b * kSteps + t0) * (size_t)kUnits + u0;
  const v2f* xr2 = (const v2f*)(Xr + base);
  const v2f* xi2 = (const v2f*)(Xi + base);
  v2f xr[kSeg], xi[kSeg];
#pragma unroll
  for (int j = 0; j < kSeg; ++j) {
    xr[j] = xr2[j * (kUnits / 2)];
    xi[j] = xi2[j * (kUnits / 2)];
  }
  __builtin_amdgcn_sched_barrier(0);

  // per-unit rotation constants + exactly-reduced own-start angle (f64 in
  // the load shadow)
  double wdt_d[kUPT];
  float cw[kUPT], sw[kUPT], c0[kUPT], s0[kUPT], c0i[kUPT], s0i[kUPT];
#pragma unroll
  for (int k = 0; k < kUPT; ++k) {
    const double wdt = (double)Om[u0 + k] * kDT;
    wdt_d[k] = wdt;
    double sd, cd;
    sincos(wdt, &sd, &cd);
    cw[k] = (float)cd;
    sw[k] = (float)sd;
    const double ang = wdt * (double)t0;
    const double kk = rint(ang * kInv2Pi);
    const float th = (float)fma(-kk, kTwoPi, ang);
    __sincosf(th, &s0[k], &c0[k]);
    c0i[k] = c0[k];   // saved: own segment-start rotation for phase 3
    s0i[k] = s0[k];
  }

  // ---- phase 1a: compose OWN segment's linear map from the reg cache ----
  const float cdt = (float)(0.1 * kDT);
  {
    float gr[kUPT] = {1.f, 1.f}, hr[kUPT] = {0.f, 0.f};
    float pr[kUPT] = {0.f, 0.f}, qr[kUPT] = {0.f, 0.f};
#pragma unroll
    for (int j = 0; j < kSeg; ++j) {
      const float Ge = kTab.G[t0 + j];
#pragma unroll
      for (int k = 0; k < kUPT; ++k) {
        const float axi = cdt * xi[j][k];
        const float axr = cdt * xr[j][k];
        const float ge = fmaf(-axi, c0[k], 1.f);
        const float he = -axi * s0[k];
        const float pe = -axr * s0[k];
        const float qe = axr * c0[k];
        const float gt = gr[k] * ge;
        const float ht = fmaf(ge, hr[k], he);
        const float pt = fmaf(pe, gr[k], Ge * pr[k]);
        const float qt = fmaf(pe, hr[k], fmaf(Ge, qr[k], qe));
        gr[k] = gt; hr[k] = ht; pr[k] = pt; qr[k] = qt;
        const float c1 = fmaf(cw[k], c0[k], -(sw[k] * s0[k]));
        const float s1 = fmaf(cw[k], s0[k], sw[k] * c0[k]);
        c0[k] = c1; s0[k] = s1;
      }
    }
#pragma unroll
    for (int k = 0; k < kUPT; ++k) {
      const int ch = ug * kUPT + k;
      sG[sOwn][ch] = gr[k];
      sH[sOwn][ch] = hr[k];
      sP[sOwn][ch] = pr[k];
      sQ[sOwn][ch] = qr[k];
    }
  }

  // ---- phase 1b (half-1 only): recompute first-half segment segL's map,
  // streaming X (used once). Same per-segment compose order as r0. ----
  if (half) {
    const int t0x = segL * kSeg;
    float cx[kUPT], sx[kUPT];
#pragma unroll
    for (int k = 0; k < kUPT; ++k) {
      const double ang = wdt_d[k] * (double)t0x;
      const double kk = rint(ang * kInv2Pi);
      const float th = (float)fma(-kk, kTwoPi, ang);
      __sincosf(th, &sx[k], &cx[k]);
    }
    const size_t basex = ((size_t)b * kSteps + t0x) * (size_t)kUnits + u0;
    const v2f* xr2x = (const v2f*)(Xr + basex);
    const v2f* xi2x = (const v2f*)(Xi + basex);
    float ga[kUPT] = {1.f, 1.f}, ha[kUPT] = {0.f, 0.f};
    float pa[kUPT] = {0.f, 0.f}, qa[kUPT] = {0.f, 0.f};
#pragma unroll
    for (int j = 0; j < kSeg; ++j) {
      const v2f xrj = xr2x[j * (kUnits / 2)];
      const v2f xij = xi2x[j * (kUnits / 2)];
      const float Ge = kTab.G[t0x + j];
#pragma unroll
      for (int k = 0; k < kUPT; ++k) {
        const float axi = cdt * xij[k];
        const float axr = cdt * xrj[k];
        const float ge = fmaf(-axi, cx[k], 1.f);
        const float he = -axi * sx[k];
        const float pe = -axr * sx[k];
        const float qe = axr * cx[k];
        const float gt = ga[k] * ge;
        const float ht = fmaf(ge, ha[k], he);
        const float pt = fmaf(pe, ga[k], Ge * pa[k]);
        const float qt = fmaf(pe, ha[k], fmaf(Ge, qa[k], qe));
        ga[k] = gt; ha[k] = ht; pa[k] = pt; qa[k] = qt;
        const float c1 = fmaf(cw[k], cx[k], -(sw[k] * sx[k]));
        const float s1 = fmaf(cw[k], sx[k], sw[k] * cx[k]);
        cx[k] = c1; sx[k] = s1;
      }
    }
#pragma unroll
    for (int k = 0; k < kUPT; ++k) {
      const int ch = ug * kUPT + k;
      sG[segL][ch] = ga[k];
      sH[segL][ch] = ha[k];
      sP[segL][ch] = pa[k];
      sQ[segL][ch] = qa[k];
    }
  }
  __syncthreads();

  // Rows valid: half0 -> 0..63 (global 0..63), half1 -> 0..127 (global).
  const int nGrp = 8 << half;   // scan groups of 8 segments

  // ---- phase 2, level 1: compose 8-segment groups ----
  if (tid < kUBlk * nGrp) {
    const int ch = tid & (kUBlk - 1);
    const int gb = tid >> 4;
    float g = 1.f, h = 0.f, p = 0.f, q = 0.f;
#pragma unroll
    for (int i = 0; i < kGrpSeg; ++i) {
      const int sg = gb * kGrpSeg + i;
      const float mg = sG[sg][ch], mh = sH[sg][ch];
      const float mp = sP[sg][ch], mq = sQ[sg][ch];
      const float Gs = kTab.Gseg[sg];
      const float gt = mg * g;
      const float ht = fmaf(mg, h, mh);
      const float pt = fmaf(mp, g, Gs * p);
      const float qt = fmaf(mp, h, fmaf(Gs, q, mq));
      g = gt; h = ht; p = pt; q = qt;
    }
    cG[gb][ch] = g; cH[gb][ch] = h; cP[gb][ch] = p; cQ[gb][ch] = q;
  }
  __syncthreads();

  // ---- phase 2, level 2: serial scan over nGrp group maps (16 threads) ----
  if (tid < kUBlk) {
    const int ch = tid;
    float d = 0.f, rho = 0.f;
    for (int gb = 0; gb < nGrp; ++gb) {
      pD[gb][ch] = d;
      pR[gb][ch] = rho;
      const float g = cG[gb][ch], h = cH[gb][ch];
      const float p = cP[gb][ch], q = cQ[gb][ch];
      const float Gs = kTab.Gg[gb];
      const float dn = fmaf(g, d, h);
      const float rn = fmaf(p, d, fmaf(Gs, rho, q));
      d = dn; rho = rn;
    }
  }
  __syncthreads();

  // ---- phase 2, level 3: expand within groups -> per-segment (delta0,rho0) ----
  if (tid < kUBlk * nGrp) {
    const int ch = tid & (kUBlk - 1);
    const int gb = tid >> 4;
    float d = pD[gb][ch], rho = pR[gb][ch];
#pragma unroll
    for (int i = 0; i < kGrpSeg; ++i) {
      const int sg = gb * kGrpSeg + i;
      const float mg = sG[sg][ch], mh = sH[sg][ch];
      const float mp = sP[sg][ch], mq = sQ[sg][ch];
      sG[sg][ch] = d;
      sH[sg][ch] = rho;
      const float Gs = kTab.Gseg[sg];
      const float dn = fmaf(mg, d, mh);
      const float rn = fmaf(mp, d, fmaf(Gs, rho, mq));
      d = dn; rho = rn;
    }
  }
  __syncthreads();

  // ---- phase 3: seed via f32 rotation of the saved exact start angle ----
  float c[kUPT], s[kUPT], r[kUPT];
#pragma unroll
  for (int k = 0; k < kUPT; ++k) {
    const int ch = ug * kUPT + k;
    const float delta = sG[sOwn][ch];   // small deviation (~0.03 rad RMS)
    const float rho = sH[sOwn][ch];
    float sd, cd;
    __sincosf(delta, &sd, &cd);
    c[k] = fmaf(c0i[k], cd, -(s0i[k] * sd));
    s[k] = fmaf(s0i[k], cd, c0i[k] * sd);
    r[k] = kTab.rbar0[sOwn] + rho;
  }

  const float DTf = (float)kDT;
  const float nscale = -(0.1f * DTf);
  const float c01dt = 0.1f * DTf;
  v2f* zr2 = (v2f*)(Zr + base);
  v2f* zi2 = (v2f*)(Zi + base);
#pragma unroll
  for (int j = 0; j < kSeg; ++j) {
    v2f ozr, ozi;
#pragma unroll
    for (int k = 0; k < kUPT; ++k) {
      // rotate (c,s) by (w*dt + eps), eps = -0.1*dt*xi*sin(phi)
      const float eps = (xi[j][k] * nscale) * s[k];
      const float A = fmaf(-sw[k], eps, cw[k]);
      const float B = fmaf(cw[k], eps, sw[k]);
      const float c2 = fmaf(A, c[k], -(B * s[k]));
      const float s2 = fmaf(A, s[k], B * c[k]);
      // r update with OLD c,r (reference order)
      const float rr = r[k] * r[k];
      const float om1 = fmaf(-0.01f, rr, 1.f);
      const float racc = fmaf(xr[j][k] * c[k], c01dt, r[k]);
      r[k] = fmaf(om1 * r[k], DTf, racc);
      c[k] = c2; s[k] = s2;
      ozr[k] = r[k] * c[k];
      ozi[k] = r[k] * s[k];
    }
    __builtin_nontemporal_store(ozr, &zr2[j * (kUnits / 2)]);
    __builtin_nontemporal_store(ozi, &zi2[j * (kUnits / 2)]);
  }
}

extern "C" void kernel_launch(void* const* d_in, const int* in_sizes, int n_in,
                              void* d_out, int out_size, void* d_ws, size_t ws_size,
                              hipStream_t stream) {
  const float* Xr = (const float*)d_in[0];
  const float* Xi = (const float*)d_in[1];
  const float* Om = (const float*)d_in[2];
  float* Zr = (float*)d_out;
  float* Zi = (float*)d_out + (size_t)kBatch * kChainElems;

  hipLaunchKernelGGL(hopf_fused, dim3(kBlocks), dim3(kThreads), 0, stream,
                     Xr, Xi, Om, Zr, Zi);
}

// Round 8
// 123.057 us; speedup vs baseline: 1.3719x; 1.3719x over previous
//
#include <hip/hip_runtime.h>
#include <math.h>

namespace {
constexpr int kUnits = 128;
constexpr int kSteps = 2048;
constexpr int kBatch = 32;
constexpr int kSeg = 16;                       // linearization window (r0-proven)
constexpr int kNSeg = kSteps / kSeg;           // 128 segments per chain
constexpr int kUBlk = 16;                      // units per block: full 64B lines
constexpr int kUPT = 2;                        // units per thread (float2)
constexpr int kUG = kUBlk / kUPT;              // 8 u-groups
constexpr int kThreads = kUG * kNSeg;          // 1024 threads/block
constexpr int kBlocks = kBatch * (kUnits / kUBlk);  // 256 blocks (1/CU)
constexpr int kGrp = 16;                       // scan groups
constexpr int kGrpSeg = kNSeg / kGrp;          // 8 segments per group
constexpr int kPad = kUBlk + 1;                // LDS pad
constexpr double kDT = 1.0 / 173.61;
constexpr double kTwoPi = 6.283185307179586;
constexpr double kInv2Pi = 1.0 / kTwoPi;
constexpr size_t kChainElems = (size_t)kSteps * kUnits;

typedef float v2f __attribute__((ext_vector_type(2)));

// Zero-input deterministic r trajectory (identical for every chain) and the
// linear growth factors G_t = 1 + (1 - 3*beta*rbar^2)*dt, at compile time.
struct Tables {
  float G[kSteps];
  float Gseg[kNSeg];   // product of G over each segment
  float Gg[kGrp];      // product of Gseg over each scan group
  float rbar0[kNSeg];  // rbar at segment starts
};
constexpr Tables make_tables() {
  Tables tb{};
  double r = 1.0;
  for (int t = 0; t < kSteps; ++t) {
    if (t % kSeg == 0) tb.rbar0[t / kSeg] = (float)r;
    tb.G[t] = (float)(1.0 + (1.0 - 0.03 * r * r) * kDT);
    r = r + (1.0 - 0.01 * r * r) * r * kDT;
  }
  for (int s = 0; s < kNSeg; ++s) {
    double p = 1.0;
    for (int j = 0; j < kSeg; ++j) p *= (double)tb.G[s * kSeg + j];
    tb.Gseg[s] = (float)p;
  }
  for (int g = 0; g < kGrp; ++g) {
    double p = 1.0;
    for (int s = 0; s < kGrpSeg; ++s) p *= (double)tb.Gseg[g * kGrpSeg + s];
    tb.Gg[g] = (float)p;
  }
  return tb;
}
}  // namespace

__constant__ Tables kTab = make_tables();

// FINAL (round-6 verified): round-0 chassis + three validated changes.
//  * __launch_bounds__(1024, 4): VGPR cap 128 (was 64) at unchanged occupancy
//    (1 block/CU = 4 waves/SIMD either way) -> room for a REAL X reg cache.
//  * sched_barrier(0) after the load loop: forbids sinking loads into the
//    compute -> all 32 loads/thread in flight (16KB/wave) to cover ~900cy
//    HBM latency; round 0/5 codegen interleaved them (VGPR 64/60, BW 44%).
//  * phase-3 seed: f32 rotation of the saved exactly-reduced segment-start
//    (cos,sin) by the scan delta (|delta|~0.03 rad) — no f64 on the
//    post-barrier critical path. Numerically validated r5/r6 (absmax same).
// Measured r6: kernel < 41.9us (below the harness fill in top-5), harness
// 123.9us. Structural alternatives all measured worse: kUBlk=8 (r1, 2.1x
// WRITE), cooperative (r2, silent fail), 2-kernel (r3, X-read-twice tax),
// time-split recompute (r7, spill + HBM re-fetch).
__global__ __launch_bounds__(kThreads, 4)
void hopf_fused(const float* __restrict__ Xr, const float* __restrict__ Xi,
                const float* __restrict__ Om,
                float* __restrict__ Zr, float* __restrict__ Zi) {
  __shared__ float sG[kNSeg][kPad];   // maps, then delta0 after phase2
  __shared__ float sH[kNSeg][kPad];   // maps, then rho0 after phase2
  __shared__ float sP[kNSeg][kPad];
  __shared__ float sQ[kNSeg][kPad];
  __shared__ float cG[kGrp][kPad], cH[kGrp][kPad], cP[kGrp][kPad], cQ[kGrp][kPad];
  __shared__ float pD[kGrp][kPad], pR[kGrp][kPad];

  const int tid = threadIdx.x;
  const int ug = tid & (kUG - 1);     // 0..7
  const int seg = tid >> 3;           // 0..127
  const int b = blockIdx.x >> 3;      // 0..31
  const int uq = blockIdx.x & 7;      // 0..7
  const int u0 = uq * kUBlk + ug * kUPT;
  const int t0 = seg * kSeg;

  // ---- load this thread's segment inputs ONCE into registers; the
  // sched_barrier pins all 32 loads above the compute (MLP) ----
  const size_t base = ((size_t)b * kSteps + t0) * (size_t)kUnits + u0;
  const v2f* xr2 = (const v2f*)(Xr + base);
  const v2f* xi2 = (const v2f*)(Xi + base);
  v2f xr[kSeg], xi[kSeg];
#pragma unroll
  for (int j = 0; j < kSeg; ++j) {
    xr[j] = xr2[j * (kUnits / 2)];
    xi[j] = xi2[j * (kUnits / 2)];
  }
  __builtin_amdgcn_sched_barrier(0);

  // per-unit rotation constants + exactly-reduced segment-start angle
  // (f64 once; issued after the loads so it fills the latency shadow)
  float cw[kUPT], sw[kUPT], c0[kUPT], s0[kUPT], c0i[kUPT], s0i[kUPT];
#pragma unroll
  for (int k = 0; k < kUPT; ++k) {
    const double wdt = (double)Om[u0 + k] * kDT;
    double sd, cd;
    sincos(wdt, &sd, &cd);
    cw[k] = (float)cd;
    sw[k] = (float)sd;
    const double ang = wdt * (double)t0;
    const double kk = rint(ang * kInv2Pi);
    const float th = (float)fma(-kk, kTwoPi, ang);
    __sincosf(th, &s0[k], &c0[k]);
    c0i[k] = c0[k];   // saved: segment-start rotation for the phase-3 seed
    s0i[k] = s0[k];
  }

  // ---- phase 1: compose the segment's linear map per chain ----
  const float cdt = (float)(0.1 * kDT);
  float gr[kUPT] = {1.f, 1.f}, hr[kUPT] = {0.f, 0.f};
  float pr[kUPT] = {0.f, 0.f}, qr[kUPT] = {0.f, 0.f};
#pragma unroll
  for (int j = 0; j < kSeg; ++j) {
    const float Ge = kTab.G[t0 + j];
#pragma unroll
    for (int k = 0; k < kUPT; ++k) {
      const float axi = cdt * xi[j][k];
      const float axr = cdt * xr[j][k];
      const float ge = fmaf(-axi, c0[k], 1.f);  // 1 - c*xi*cos(phi0)
      const float he = -axi * s0[k];            // -c*xi*sin(phi0)
      const float pe = -axr * s0[k];            // -c*xr*sin(phi0)
      const float qe = axr * c0[k];             //  c*xr*cos(phi0)
      const float g2 = gr[k] * ge;
      const float h2 = fmaf(ge, hr[k], he);
      const float p2 = fmaf(pe, gr[k], Ge * pr[k]);
      const float q2 = fmaf(pe, hr[k], fmaf(Ge, qr[k], qe));
      gr[k] = g2; hr[k] = h2; pr[k] = p2; qr[k] = q2;
      const float c1 = fmaf(cw[k], c0[k], -(sw[k] * s0[k]));
      const float s1 = fmaf(cw[k], s0[k], sw[k] * c0[k]);
      c0[k] = c1; s0[k] = s1;
    }
  }
#pragma unroll
  for (int k = 0; k < kUPT; ++k) {
    const int ch = ug * kUPT + k;
    sG[seg][ch] = gr[k];
    sH[seg][ch] = hr[k];
    sP[seg][ch] = pr[k];
    sQ[seg][ch] = qr[k];
  }
  __syncthreads();

  // ---- phase 2, level 1: compose 8-segment groups (256 threads) ----
  if (tid < kUBlk * kGrp) {
    const int ch = tid & (kUBlk - 1);
    const int gb = tid >> 4;
    float g = 1.f, h = 0.f, p = 0.f, q = 0.f;
#pragma unroll
    for (int i = 0; i < kGrpSeg; ++i) {
      const int sg = gb * kGrpSeg + i;
      const float mg = sG[sg][ch], mh = sH[sg][ch];
      const float mp = sP[sg][ch], mq = sQ[sg][ch];
      const float Gs = kTab.Gseg[sg];
      const float g2 = mg * g;
      const float h2 = fmaf(mg, h, mh);
      const float p2 = fmaf(mp, g, Gs * p);
      const float q2 = fmaf(mp, h, fmaf(Gs, q, mq));
      g = g2; h = h2; p = p2; q = q2;
    }
    cG[gb][ch] = g; cH[gb][ch] = h; cP[gb][ch] = p; cQ[gb][ch] = q;
  }
  __syncthreads();

  // ---- phase 2, level 2: scan 16 group maps per chain (16 threads) ----
  if (tid < kUBlk) {
    const int ch = tid;
    float d = 0.f, rho = 0.f;
#pragma unroll
    for (int gb = 0; gb < kGrp; ++gb) {
      pD[gb][ch] = d;
      pR[gb][ch] = rho;
      const float g = cG[gb][ch], h = cH[gb][ch];
      const float p = cP[gb][ch], q = cQ[gb][ch];
      const float Gs = kTab.Gg[gb];
      const float dn = fmaf(g, d, h);
      const float rn = fmaf(p, d, fmaf(Gs, rho, q));
      d = dn; rho = rn;
    }
  }
  __syncthreads();

  // ---- phase 2, level 3: expand within groups; overwrite sG/sH with
  // per-segment start states (delta0, rho0) ----
  if (tid < kUBlk * kGrp) {
    const int ch = tid & (kUBlk - 1);
    const int gb = tid >> 4;
    float d = pD[gb][ch], rho = pR[gb][ch];
#pragma unroll
    for (int i = 0; i < kGrpSeg; ++i) {
      const int sg = gb * kGrpSeg + i;
      const float mg = sG[sg][ch], mh = sH[sg][ch];
      const float mp = sP[sg][ch], mq = sQ[sg][ch];
      sG[sg][ch] = d;
      sH[sg][ch] = rho;
      const float Gs = kTab.Gseg[sg];
      const float dn = fmaf(mg, d, mh);
      const float rn = fmaf(mp, d, fmaf(Gs, rho, mq));
      d = dn; rho = rn;
    }
  }
  __syncthreads();

  // ---- phase 3: seed via f32 rotation of the saved exact start angle ----
  float c[kUPT], s[kUPT], r[kUPT];
#pragma unroll
  for (int k = 0; k < kUPT; ++k) {
    const int ch = ug * kUPT + k;
    const float delta = sG[seg][ch];   // small deviation (~0.03 rad RMS)
    const float rho = sH[seg][ch];
    float sd, cd;
    __sincosf(delta, &sd, &cd);
    c[k] = fmaf(c0i[k], cd, -(s0i[k] * sd));
    s[k] = fmaf(s0i[k], cd, c0i[k] * sd);
    r[k] = kTab.rbar0[seg] + rho;
  }

  const float DTf = (float)kDT;
  const float nscale = -(0.1f * DTf);
  const float c01dt = 0.1f * DTf;
  v2f* zr2 = (v2f*)(Zr + base);
  v2f* zi2 = (v2f*)(Zi + base);
#pragma unroll
  for (int j = 0; j < kSeg; ++j) {
    v2f ozr, ozi;
#pragma unroll
    for (int k = 0; k < kUPT; ++k) {
      // rotate (c,s) by (w*dt + eps), eps = -0.1*dt*xi*sin(phi)
      const float eps = (xi[j][k] * nscale) * s[k];
      const float A = fmaf(-sw[k], eps, cw[k]);
      const float B = fmaf(cw[k], eps, sw[k]);
      const float c2 = fmaf(A, c[k], -(B * s[k]));
      const float s2 = fmaf(A, s[k], B * c[k]);
      // r update with OLD c,r (reference order)
      const float rr = r[k] * r[k];
      const float om1 = fmaf(-0.01f, rr, 1.f);
      const float racc = fmaf(xr[j][k] * c[k], c01dt, r[k]);
      r[k] = fmaf(om1 * r[k], DTf, racc);
      c[k] = c2; s[k] = s2;
      ozr[k] = r[k] * c[k];
      ozi[k] = r[k] * s[k];
    }
    __builtin_nontemporal_store(ozr, &zr2[j * (kUnits / 2)]);
    __builtin_nontemporal_store(ozi, &zi2[j * (kUnits / 2)]);
  }
}

extern "C" void kernel_launch(void* const* d_in, const int* in_sizes, int n_in,
                              void* d_out, int out_size, void* d_ws, size_t ws_size,
                              hipStream_t stream) {
  const float* Xr = (const float*)d_in[0];
  const float* Xi = (const float*)d_in[1];
  const float* Om = (const float*)d_in[2];
  float* Zr = (float*)d_out;
  float* Zi = (float*)d_out + (size_t)kBatch * kChainElems;

  hipLaunchKernelGGL(hopf_fused, dim3(kBlocks), dim3(kThreads), 0, stream,
                     Xr, Xi, Om, Zr, Zi);
}